// Round 1
// baseline (155.920 us; speedup 1.0000x reference)
//
#include <hip/hip_runtime.h>

#define BATCH 8192
#define SEQ   80
#define EMBD  100
#define UNITS 64
#define MB    16
#define NTHREADS 256

typedef __attribute__((ext_vector_type(8))) short short8;
typedef __attribute__((ext_vector_type(4))) float floatx4;

__device__ __forceinline__ short f2bf(float f) {
  unsigned u = __float_as_uint(f);
  u += 0x7FFFu + ((u >> 16) & 1u);   // round-to-nearest-even
  return (short)(u >> 16);
}
__device__ __forceinline__ float bf2f(short s) {
  return __uint_as_float(((unsigned)(unsigned short)s) << 16);
}
__device__ __forceinline__ float fast_tanh(float x) {
  float e = __expf(2.0f * x);
  return 1.0f - __fdividef(2.0f, e + 1.0f);
}
__device__ __forceinline__ void store_bf4(short* dst, float4 v) {
  union { short s[4]; int2 i2; } p;
  p.s[0] = f2bf(v.x); p.s[1] = f2bf(v.y); p.s[2] = f2bf(v.z); p.s[3] = f2bf(v.w);
  *(int2*)dst = p.i2;
}

// Layout facts used (HW-verified per guide):
//  A-frag: A[m = lane&15][k = (lane>>4)*8 + j], j = elem 0..7  (k contiguous in LDS)
//  B-frag: B[k = (lane>>4)*8 + j][n = lane&15]  -> load W^T rows [n][k] == W[k][n] column
//  C/D   : D[row = (lane>>4)*4 + reg][col = lane&15]
__launch_bounds__(NTHREADS, 2)
__global__ void rnn2_kernel(const int* __restrict__ tokens,
                            const float* __restrict__ emb,
                            const float* __restrict__ W1x,
                            const float* __restrict__ W1h,
                            const float* __restrict__ b1,
                            const float* __restrict__ W2x,
                            const float* __restrict__ W2h,
                            const float* __restrict__ b2,
                            const float* __restrict__ Wd,
                            const float* __restrict__ bd,
                            float* __restrict__ out)
{
  // stride pads: X row = 136 shorts (272 B), H row = 72 shorts (144 B)
  // both are 16B multiples and ≡ 16B (mod 128B) -> balanced banks for b128 frag reads
  __shared__ __align__(16) short Xb[2][MB][136];   // [m][k] bf16, double-buffered
  __shared__ __align__(16) short H1s[2][MB][72];   // [m][unit] bf16
  __shared__ __align__(16) short H2s[2][MB][72];
  __shared__ __align__(16) int   tok[MB][SEQ];

  const int tid  = threadIdx.x;
  const int wave = tid >> 6;
  const int lane = tid & 63;
  const int li   = lane & 15;
  const int quad = lane >> 4;
  const int u    = wave * 16 + li;          // unit column this lane produces
  const int rowBase = blockIdx.x * MB;

  // ---- stage tokens: this block's rows are one contiguous [MB][SEQ] chunk ----
  {
    const int4* tp = (const int4*)(tokens + rowBase * SEQ);
    int4* tl = (int4*)(&tok[0][0]);
    for (int i = tid; i < MB * SEQ / 4; i += NTHREADS) tl[i] = tp[i];
  }
  // ---- zero X (pad region must be finite: NaN*0 = NaN in MFMA) + H state ----
  {
    int* px = (int*)(&Xb[0][0][0]);
    for (int i = tid; i < 2 * MB * 136 / 2; i += NTHREADS) px[i] = 0;
    int* p1 = (int*)(&H1s[0][0][0]);
    for (int i = tid; i < 2 * MB * 72 / 2; i += NTHREADS) p1[i] = 0;
    int* p2 = (int*)(&H2s[0][0][0]);
    for (int i = tid; i < 2 * MB * 72 / 2; i += NTHREADS) p2[i] = 0;
  }

  // ---- weight B-fragments in registers, held for the whole kernel ----
  short8 w1x[4], w1h[2], w2x[2], w2h[2];
  #pragma unroll
  for (int kc = 0; kc < 4; ++kc) {
    short8 f;
    #pragma unroll
    for (int j = 0; j < 8; ++j) {
      const int k = kc * 32 + quad * 8 + j;
      f[j] = f2bf(k < EMBD ? W1x[k * UNITS + u] : 0.0f);  // zero-pad k in [100,128)
    }
    w1x[kc] = f;
  }
  #pragma unroll
  for (int kc = 0; kc < 2; ++kc) {
    short8 f, g, h;
    #pragma unroll
    for (int j = 0; j < 8; ++j) {
      const int k = kc * 32 + quad * 8 + j;
      f[j] = f2bf(W1h[k * UNITS + u]);
      g[j] = f2bf(W2x[k * UNITS + u]);
      h[j] = f2bf(W2h[k * UNITS + u]);
    }
    w1h[kc] = f; w2x[kc] = g; w2h[kc] = h;
  }
  const float bias1 = b1[u];
  const float bias2 = b2[u];

  __syncthreads();   // tokens + zeroed buffers visible

  // ---- gather X_0 (400 float4 tasks: 16 rows x 25 chunks) ----
  const float4* emb4 = (const float4*)emb;   // emb row = 25 float4 (400 B, aligned)
  {
    int tau = tid;   // tid < 256 < 400: always valid
    int r = tau / 25, c = tau % 25;
    store_bf4(&Xb[0][r][c * 4], emb4[tok[r][0] * 25 + c]);
    tau = tid + NTHREADS;
    if (tau < MB * 25) {
      r = tau / 25; c = tau % 25;
      store_bf4(&Xb[0][r][c * 4], emb4[tok[r][0] * 25 + c]);
    }
  }
  __syncthreads();   // X_0 visible

  const int  r0 = tid / 25, c0 = tid % 25;
  const bool has1 = (tid + NTHREADS) < MB * 25;
  const int  r1 = (tid + NTHREADS) / 25, c1 = (tid + NTHREADS) % 25;

  for (int t = 0; t < SEQ; ++t) {
    const int cur = t & 1, nxt = cur ^ 1;

    // prefetch X_{t+1} from emb (L2-resident); stored after the mid-step barrier
    float4 pf0, pf1;
    const bool pf = (t + 1) < SEQ;
    if (pf) {
      pf0 = emb4[tok[r0][t + 1] * 25 + c0];
      if (has1) pf1 = emb4[tok[r1][t + 1] * 25 + c1];
    }

    // ---- layer 1: h1 = tanh(x_t @ W1x + h1_prev @ W1h + b1) ----
    floatx4 acc = {bias1, bias1, bias1, bias1};
    #pragma unroll
    for (int kc = 0; kc < 4; ++kc) {
      const short8 a = *(const short8*)(&Xb[cur][li][kc * 32 + quad * 8]);
      acc = __builtin_amdgcn_mfma_f32_16x16x32_bf16(a, w1x[kc], acc, 0, 0, 0);
    }
    #pragma unroll
    for (int kc = 0; kc < 2; ++kc) {
      const short8 a = *(const short8*)(&H1s[nxt][li][kc * 32 + quad * 8]);
      acc = __builtin_amdgcn_mfma_f32_16x16x32_bf16(a, w1h[kc], acc, 0, 0, 0);
    }
    #pragma unroll
    for (int i = 0; i < 4; ++i)
      H1s[cur][quad * 4 + i][u] = f2bf(fast_tanh(acc[i]));

    __syncthreads();   // H1_t complete (unit halves come from different waves)

    // ---- layer 2: h2 = tanh(h1_t @ W2x + h2_prev @ W2h + b2) ----
    floatx4 acc2 = {bias2, bias2, bias2, bias2};
    #pragma unroll
    for (int kc = 0; kc < 2; ++kc) {
      const short8 a = *(const short8*)(&H1s[cur][li][kc * 32 + quad * 8]);
      acc2 = __builtin_amdgcn_mfma_f32_16x16x32_bf16(a, w2x[kc], acc2, 0, 0, 0);
    }
    #pragma unroll
    for (int kc = 0; kc < 2; ++kc) {
      const short8 a = *(const short8*)(&H2s[nxt][li][kc * 32 + quad * 8]);
      acc2 = __builtin_amdgcn_mfma_f32_16x16x32_bf16(a, w2h[kc], acc2, 0, 0, 0);
    }
    #pragma unroll
    for (int i = 0; i < 4; ++i)
      H2s[cur][quad * 4 + i][u] = f2bf(fast_tanh(acc2[i]));

    // commit prefetched X_{t+1} into the other X buffer
    if (pf) {
      store_bf4(&Xb[nxt][r0][c0 * 4], pf0);
      if (has1) store_bf4(&Xb[nxt][r1][c1 * 4], pf1);
    }
    __syncthreads();   // H2_t + X_{t+1} visible
  }

  // ---- head: sigmoid(h2_last @ Wd + bd) ----
  if (tid < MB) {
    const short* hrow = &H2s[(SEQ - 1) & 1][tid][0];
    float acc = bd[0];
    #pragma unroll
    for (int uu = 0; uu < UNITS; ++uu)
      acc += bf2f(hrow[uu]) * Wd[uu];
    out[rowBase + tid] = 1.0f / (1.0f + __expf(-acc));
  }
}

extern "C" void kernel_launch(void* const* d_in, const int* in_sizes, int n_in,
                              void* d_out, int out_size, void* d_ws, size_t ws_size,
                              hipStream_t stream) {
  const int*   tokens = (const int*)d_in[0];
  const float* emb    = (const float*)d_in[1];
  const float* W1x    = (const float*)d_in[2];
  const float* W1h    = (const float*)d_in[3];
  const float* b1     = (const float*)d_in[4];
  const float* W2x    = (const float*)d_in[5];
  const float* W2h    = (const float*)d_in[6];
  const float* b2     = (const float*)d_in[7];
  const float* Wd     = (const float*)d_in[8];
  const float* bd     = (const float*)d_in[9];
  float* out = (float*)d_out;

  dim3 grid(BATCH / MB);     // 512 workgroups -> 2 per CU
  dim3 block(NTHREADS);
  rnn2_kernel<<<grid, block, 0, stream>>>(tokens, emb, W1x, W1h, b1,
                                          W2x, W2h, b2, Wd, bd, out);
}

// Round 2
// 138.548 us; speedup vs baseline: 1.1254x; 1.1254x over previous
//
#include <hip/hip_runtime.h>

#define TOTALW 10000
#define BATCH 8192
#define SEQ   80
#define EMBD  100
#define UNITS 64
#define MB    16
#define NTHREADS 256

typedef __attribute__((ext_vector_type(8))) short short8;
typedef __attribute__((ext_vector_type(4))) float floatx4;

__device__ __forceinline__ short f2bf(float f) {
  unsigned u = __float_as_uint(f);
  u += 0x7FFFu + ((u >> 16) & 1u);   // RNE
  return (short)(u >> 16);
}
__device__ __forceinline__ float bf2f(short s) {
  return __uint_as_float(((unsigned)(unsigned short)s) << 16);
}
__device__ __forceinline__ float fast_tanh(float x) {
#if __has_builtin(__builtin_amdgcn_exp2f) && __has_builtin(__builtin_amdgcn_rcpf)
  // tanh(x) = 1 - 2/(e^{2x}+1);  e^{2x} = 2^(x * 2*log2 e)
  float e = __builtin_amdgcn_exp2f(2.8853900817779268f * x);
  float r = __builtin_amdgcn_rcpf(e + 1.0f);
  return __builtin_fmaf(-2.0f, r, 1.0f);
#else
  float e = __expf(2.0f * x);
  return 1.0f - __fdividef(2.0f, e + 1.0f);
#endif
}

// ---- kernel 1: xw[v][u] = emb[v,:] . W1x[:,u] + b1[u]  (fp32, into d_ws) ----
__launch_bounds__(256)
__global__ void emb_proj(const float* __restrict__ emb,
                         const float* __restrict__ W1x,
                         const float* __restrict__ b1,
                         float* __restrict__ xw) {
  int gid = blockIdx.x * 256 + threadIdx.x;
  if (gid >= TOTALW * UNITS) return;
  int v = gid >> 6, u = gid & 63;
  const float* er = emb + v * EMBD;
  float acc = b1[u];
  #pragma unroll 5
  for (int k = 0; k < EMBD; ++k)
    acc = __builtin_fmaf(er[k], W1x[k * UNITS + u], acc);
  xw[gid] = acc;
}

// Layout facts (HW-verified per guide):
//  A-frag: A[m = lane&15][k = (lane>>4)*8 + j]   (k contiguous in LDS)
//  B-frag: B[k = (lane>>4)*8 + j][n = lane&15]
//  C/D   : D[row = (lane>>4)*4 + reg][col = lane&15]
__launch_bounds__(NTHREADS, 2)
__global__ void rnn2_kernel(const int* __restrict__ tokens,
                            const float* __restrict__ xw,    // [TOTALW][64] = emb@W1x + b1
                            const float* __restrict__ W1h,
                            const float* __restrict__ W2x,
                            const float* __restrict__ W2h,
                            const float* __restrict__ b2,
                            const float* __restrict__ Wd,
                            const float* __restrict__ bd,
                            float* __restrict__ out)
{
  // H row stride 72 shorts (144 B, 16B-aligned)
  __shared__ __align__(16) short H1s[2][MB][72];   // [m][unit] bf16
  __shared__ __align__(16) short H2s[2][MB][72];
  __shared__ __align__(16) int   tok[MB][SEQ];

  const int tid  = threadIdx.x;
  const int wave = tid >> 6;
  const int lane = tid & 63;
  const int li   = lane & 15;
  const int quad = lane >> 4;
  const int q4   = quad * 4;
  const int u    = wave * 16 + li;          // unit column this lane produces
  const int rowBase = blockIdx.x * MB;

  // ---- stage tokens (contiguous [MB][SEQ] chunk) ----
  {
    const int4* tp = (const int4*)(tokens + rowBase * SEQ);
    int4* tl = (int4*)(&tok[0][0]);
    for (int i = tid; i < MB * SEQ / 4; i += NTHREADS) tl[i] = tp[i];
  }
  // ---- zero H2 buf[1] (h2_{-1} = 0) ----
  {
    int* p2 = (int*)(&H2s[1][0][0]);
    for (int i = tid; i < MB * 72 / 2; i += NTHREADS) p2[i] = 0;
  }

  // ---- weight B-fragments in registers for the whole kernel ----
  short8 w1h[2], w2x[2], w2h[2];
  #pragma unroll
  for (int kc = 0; kc < 2; ++kc) {
    short8 f, g, h;
    #pragma unroll
    for (int j = 0; j < 8; ++j) {
      const int k = kc * 32 + quad * 8 + j;
      f[j] = f2bf(W1h[k * UNITS + u]);
      g[j] = f2bf(W2x[k * UNITS + u]);
      h[j] = f2bf(W2h[k * UNITS + u]);
    }
    w1h[kc] = f; w2x[kc] = g; w2h[kc] = h;
  }
  const float bias2 = b2[u];

  __syncthreads();   // tokens + zeroed H2 visible

  // ---- prologue: h1_0 = tanh(xw[tok_0])  (h1_{-1} = 0, so no MFMA) ----
  float xw_cur[4];
  {
    #pragma unroll
    for (int i = 0; i < 4; ++i) {
      const int tk = tok[q4 + i][0];
      const float v = xw[tk * UNITS + u];
      H1s[0][q4 + i][u] = f2bf(fast_tanh(v));
    }
    // prefetch xw for step 1
    #pragma unroll
    for (int i = 0; i < 4; ++i) {
      const int tk = tok[q4 + i][1];
      xw_cur[i] = xw[tk * UNITS + u];
    }
  }
  __syncthreads();   // h1_0 visible

  // ---- main loop: iteration t computes h2_t and h1_{t+1} (both need h1_t) ----
  for (int t = 0; t < SEQ - 1; ++t) {
    const int cur = t & 1, nxt = cur ^ 1;

    // prefetch xw for step t+2 (registers; used next iteration)
    float xwn[4] = {0.f, 0.f, 0.f, 0.f};
    if (t < SEQ - 2) {
      #pragma unroll
      for (int i = 0; i < 4; ++i) {
        const int tk = tok[q4 + i][t + 2];
        xwn[i] = xw[tk * UNITS + u];
      }
    }

    // shared A-fragments
    const short8 h1a0 = *(const short8*)(&H1s[cur][li][quad * 8]);
    const short8 h1a1 = *(const short8*)(&H1s[cur][li][32 + quad * 8]);
    const short8 h2a0 = *(const short8*)(&H2s[nxt][li][quad * 8]);
    const short8 h2a1 = *(const short8*)(&H2s[nxt][li][32 + quad * 8]);

    // h2_t = tanh(h1_t @ W2x + h2_{t-1} @ W2h + b2)
    floatx4 acc2 = {bias2, bias2, bias2, bias2};
    acc2 = __builtin_amdgcn_mfma_f32_16x16x32_bf16(h1a0, w2x[0], acc2, 0, 0, 0);
    acc2 = __builtin_amdgcn_mfma_f32_16x16x32_bf16(h1a1, w2x[1], acc2, 0, 0, 0);
    acc2 = __builtin_amdgcn_mfma_f32_16x16x32_bf16(h2a0, w2h[0], acc2, 0, 0, 0);
    acc2 = __builtin_amdgcn_mfma_f32_16x16x32_bf16(h2a1, w2h[1], acc2, 0, 0, 0);

    // h1_{t+1} = tanh(xw_{t+1} + h1_t @ W1h)   (xw already includes b1)
    floatx4 acc1 = {xw_cur[0], xw_cur[1], xw_cur[2], xw_cur[3]};
    acc1 = __builtin_amdgcn_mfma_f32_16x16x32_bf16(h1a0, w1h[0], acc1, 0, 0, 0);
    acc1 = __builtin_amdgcn_mfma_f32_16x16x32_bf16(h1a1, w1h[1], acc1, 0, 0, 0);

    #pragma unroll
    for (int i = 0; i < 4; ++i) {
      H2s[cur][q4 + i][u] = f2bf(fast_tanh(acc2[i]));
      H1s[nxt][q4 + i][u] = f2bf(fast_tanh(acc1[i]));
    }
    #pragma unroll
    for (int i = 0; i < 4; ++i) xw_cur[i] = xwn[i];

    __syncthreads();   // h2_t, h1_{t+1} visible; protects WAR on next iter's writes
  }

  // ---- epilogue: h2_{SEQ-1} ----
  {
    const int cur = (SEQ - 1) & 1, nxt = cur ^ 1;
    const short8 h1a0 = *(const short8*)(&H1s[cur][li][quad * 8]);
    const short8 h1a1 = *(const short8*)(&H1s[cur][li][32 + quad * 8]);
    const short8 h2a0 = *(const short8*)(&H2s[nxt][li][quad * 8]);
    const short8 h2a1 = *(const short8*)(&H2s[nxt][li][32 + quad * 8]);
    floatx4 acc2 = {bias2, bias2, bias2, bias2};
    acc2 = __builtin_amdgcn_mfma_f32_16x16x32_bf16(h1a0, w2x[0], acc2, 0, 0, 0);
    acc2 = __builtin_amdgcn_mfma_f32_16x16x32_bf16(h1a1, w2x[1], acc2, 0, 0, 0);
    acc2 = __builtin_amdgcn_mfma_f32_16x16x32_bf16(h2a0, w2h[0], acc2, 0, 0, 0);
    acc2 = __builtin_amdgcn_mfma_f32_16x16x32_bf16(h2a1, w2h[1], acc2, 0, 0, 0);
    #pragma unroll
    for (int i = 0; i < 4; ++i)
      H2s[cur][q4 + i][u] = f2bf(fast_tanh(acc2[i]));
  }
  __syncthreads();

  // ---- head: sigmoid(h2_last @ Wd + bd) ----
  if (tid < MB) {
    const short* hrow = &H2s[(SEQ - 1) & 1][tid][0];
    float acc = bd[0];
    #pragma unroll
    for (int uu = 0; uu < UNITS; ++uu)
      acc += bf2f(hrow[uu]) * Wd[uu];
    out[rowBase + tid] = 1.0f / (1.0f + __expf(-acc));
  }
}

extern "C" void kernel_launch(void* const* d_in, const int* in_sizes, int n_in,
                              void* d_out, int out_size, void* d_ws, size_t ws_size,
                              hipStream_t stream) {
  const int*   tokens = (const int*)d_in[0];
  const float* emb    = (const float*)d_in[1];
  const float* W1x    = (const float*)d_in[2];
  const float* W1h    = (const float*)d_in[3];
  const float* b1     = (const float*)d_in[4];
  const float* W2x    = (const float*)d_in[5];
  const float* W2h    = (const float*)d_in[6];
  const float* b2     = (const float*)d_in[7];
  const float* Wd     = (const float*)d_in[8];
  const float* bd     = (const float*)d_in[9];
  float* out = (float*)d_out;
  float* xw  = (float*)d_ws;   // 10000*64*4 = 2.56 MB scratch

  emb_proj<<<(TOTALW * UNITS + 255) / 256, 256, 0, stream>>>(emb, W1x, b1, xw);

  dim3 grid(BATCH / MB);       // 512 workgroups
  dim3 block(NTHREADS);
  rnn2_kernel<<<grid, block, 0, stream>>>(tokens, xw, W1h, W2x, W2h, b2, Wd, bd, out);
}

// Round 3
// 138.253 us; speedup vs baseline: 1.1278x; 1.0021x over previous
//
#include <hip/hip_runtime.h>
#include <hip/hip_bf16.h>

#define TOTALW 10000
#define BATCH 8192
#define SEQ   80
#define EMBD  100
#define UNITS 64
#define MB    16
#define NTHREADS 256
#define TOKPAD 84   // int stride: 84%32=20 -> li*20 mod 32 spreads 8 banks (was 8-way at 80)

typedef __attribute__((ext_vector_type(8))) short short8;
typedef __attribute__((ext_vector_type(4))) float floatx4;

__device__ __forceinline__ short f2bf(float f) {
  unsigned u = __float_as_uint(f);
  u += 0x7FFFu + ((u >> 16) & 1u);   // RNE
  return (short)(u >> 16);
}
__device__ __forceinline__ float bf2f(short s) {
  return __uint_as_float(((unsigned)(unsigned short)s) << 16);
}
__device__ __forceinline__ unsigned pk2bf(float a, float b) {
  __hip_bfloat162 h = __float22bfloat162_rn(float2{a, b});
  union { __hip_bfloat162 h2; unsigned u; } c; c.h2 = h;
  return c.u;
}
__device__ __forceinline__ float fast_tanh(float x) {
  // tanh(x) = 1 - 2/(e^{2x}+1);  e^{2x} = 2^(x * 2*log2e)
  float e = __builtin_expf(2.0f * x);   // lowers to v_exp_f32 with -ffast-math-ish HIP default? keep explicit:
  return 1.0f - 2.0f / (e + 1.0f);
}
__device__ __forceinline__ float fast_tanh2(float x) {
  float e = __expf(2.0f * x);
  float r = __frcp_rn(e + 1.0f);
  return __builtin_fmaf(-2.0f, r, 1.0f);
}
#define TANH fast_tanh2

// ---- kernel 1: xw = emb @ W1x + b1 via MFMA (bf16 in, fp32 out) ----
__launch_bounds__(256)
__global__ void emb_proj_mfma(const float* __restrict__ emb,
                              const float* __restrict__ W1x,
                              const float* __restrict__ b1,
                              float* __restrict__ xw) {
  __shared__ __align__(16) short Es[16][128];   // [row][k] bf16, k padded to 128
  const int tid  = threadIdx.x;
  const int wave = tid >> 6;
  const int lane = tid & 63;
  const int li   = lane & 15;
  const int quad = lane >> 4;
  const int q4   = quad * 4;
  const int rowBase = blockIdx.x * 16;          // 625 * 16 = 10000 exact

  // stage emb rows -> bf16 LDS (16 rows x 25 float4)
  for (int task = tid; task < 16 * 25; task += 256) {
    const int r = task / 25, c = task % 25;
    const float4 v = *(const float4*)(emb + (rowBase + r) * EMBD + c * 4);
    const unsigned p0 = pk2bf(v.x, v.y), p1 = pk2bf(v.z, v.w);
    *(int2*)(&Es[r][c * 4]) = make_int2((int)p0, (int)p1);
  }
  // zero k in [100,128): 16 rows x 28 shorts = 224 int tasks
  for (int task = tid; task < 224; task += 256) {
    const int r = task / 14, c = task % 14;
    *(int*)(&Es[r][100 + c * 2]) = 0;
  }
  // B-frags of W1x for this wave's 16 units (k zero-padded past 100)
  short8 bw[4];
  #pragma unroll
  for (int kc = 0; kc < 4; ++kc) {
    short8 f;
    #pragma unroll
    for (int j = 0; j < 8; ++j) {
      const int k = kc * 32 + quad * 8 + j;
      f[j] = (k < EMBD) ? f2bf(W1x[k * UNITS + wave * 16 + li]) : (short)0;
    }
    bw[kc] = f;
  }
  const float bb = b1[wave * 16 + li];
  __syncthreads();

  floatx4 acc = {bb, bb, bb, bb};
  #pragma unroll
  for (int kc = 0; kc < 4; ++kc) {
    const short8 a = *(const short8*)(&Es[li][kc * 32 + quad * 8]);
    acc = __builtin_amdgcn_mfma_f32_16x16x32_bf16(a, bw[kc], acc, 0, 0, 0);
  }
  #pragma unroll
  for (int i = 0; i < 4; ++i)   // D[row=q4+i][unit=wave*16+li]
    xw[(rowBase + q4 + i) * UNITS + wave * 16 + li] = acc[i];
}

// ---- kernel 2: the recurrence, operand-swapped MFMA ----
// mfma(A=W^T frag, B=h^T frag): D[m=unit_out][n=batch_row]
//  weight A-frag: lane li -> unit_out = w*16+li; elem j -> unit_in = kc*32+quad*8+j
//                 value = W[unit_in][unit_out]  (same loads as B-frag form)
//  h B-frag: lane li -> row li; elem j -> unit_in  => ds_read_b128 of H[li][kc*32+quad*8]
//  D: lane holds row li, units w*16+q4+{0..3}  => xw gather is one float4,
//     h writeback is one packed b64 store
__launch_bounds__(NTHREADS, 2)
__global__ void rnn2_kernel(const int* __restrict__ tokens,
                            const float* __restrict__ xw,
                            const float* __restrict__ W1h,
                            const float* __restrict__ W2x,
                            const float* __restrict__ W2h,
                            const float* __restrict__ b2,
                            const float* __restrict__ Wd,
                            const float* __restrict__ bd,
                            float* __restrict__ out)
{
  __shared__ __align__(16) short H1s[2][MB][72];   // [row][unit] bf16, stride 144 B
  __shared__ __align__(16) short H2s[2][MB][72];
  __shared__ __align__(16) int   tok[MB][TOKPAD];

  const int tid  = threadIdx.x;
  const int wave = tid >> 6;
  const int lane = tid & 63;
  const int li   = lane & 15;
  const int quad = lane >> 4;
  const int q4   = quad * 4;
  const int u     = wave * 16 + li;    // for weight-frag loads
  const int ubase = wave * 16 + q4;    // unit base of this lane's 4 D elements
  const int rowBase = blockIdx.x * MB;

  // ---- stage tokens [MB][80] -> LDS [MB][84] (16B-aligned int4 copies) ----
  for (int task = tid; task < MB * 20; task += NTHREADS) {
    const int r = task / 20, c = task % 20;
    *(int4*)(&tok[r][c * 4]) = *(const int4*)(tokens + (rowBase + r) * SEQ + c * 4);
  }
  // ---- zero H2s[1] (h2_{-1} = 0) ----
  for (int i = tid; i < MB * 72 / 2; i += NTHREADS)
    ((int*)&H2s[1][0][0])[i] = 0;

  // ---- weight A-frags (register-resident whole kernel) ----
  short8 w1h[2], w2x[2], w2h[2];
  #pragma unroll
  for (int kc = 0; kc < 2; ++kc) {
    short8 f, g, h;
    #pragma unroll
    for (int j = 0; j < 8; ++j) {
      const int k = kc * 32 + quad * 8 + j;
      f[j] = f2bf(W1h[k * UNITS + u]);
      g[j] = f2bf(W2x[k * UNITS + u]);
      h[j] = f2bf(W2h[k * UNITS + u]);
    }
    w1h[kc] = f; w2x[kc] = g; w2h[kc] = h;
  }
  const float4 b2f = *(const float4*)(b2 + ubase);   // b2[ubase..ubase+3]

  __syncthreads();   // tokens + zeroed H2 visible (full fence ok, once)

  // ---- prologue: h1_0 = tanh(xw[tok_0]); prefetch xw_1 ----
  float4 xw_cur;
  {
    const int tk0 = tok[li][0];
    const float4 x0 = *(const float4*)(xw + tk0 * UNITS + ubase);
    const unsigned p0 = pk2bf(TANH(x0.x), TANH(x0.y));
    const unsigned p1 = pk2bf(TANH(x0.z), TANH(x0.w));
    *(int2*)(&H1s[0][li][ubase]) = make_int2((int)p0, (int)p1);
    const int tk1 = tok[li][1];
    xw_cur = *(const float4*)(xw + tk1 * UNITS + ubase);
  }
  asm volatile("s_waitcnt lgkmcnt(0)\n\ts_barrier" ::: "memory");

  // one step: computes h2_t and h1_{t+1}; PF=1 -> prefetch xw_{t+2}
#define STEP(T, CUR, NXT, PF)                                                   \
  {                                                                             \
    float4 xwn;                                                                 \
    if (PF) {                                                                   \
      const int tk = tok[li][(T) + 2];                                          \
      xwn = *(const float4*)(xw + tk * UNITS + ubase);                          \
    }                                                                           \
    const short8 h1a0 = *(const short8*)(&H1s[CUR][li][quad * 8]);              \
    const short8 h1a1 = *(const short8*)(&H1s[CUR][li][32 + quad * 8]);         \
    const short8 h2a0 = *(const short8*)(&H2s[NXT][li][quad * 8]);              \
    const short8 h2a1 = *(const short8*)(&H2s[NXT][li][32 + quad * 8]);         \
    floatx4 acc2 = {b2f.x, b2f.y, b2f.z, b2f.w};                                \
    acc2 = __builtin_amdgcn_mfma_f32_16x16x32_bf16(w2x[0], h1a0, acc2, 0, 0, 0);\
    acc2 = __builtin_amdgcn_mfma_f32_16x16x32_bf16(w2x[1], h1a1, acc2, 0, 0, 0);\
    acc2 = __builtin_amdgcn_mfma_f32_16x16x32_bf16(w2h[0], h2a0, acc2, 0, 0, 0);\
    acc2 = __builtin_amdgcn_mfma_f32_16x16x32_bf16(w2h[1], h2a1, acc2, 0, 0, 0);\
    floatx4 acc1 = {xw_cur.x, xw_cur.y, xw_cur.z, xw_cur.w};                    \
    acc1 = __builtin_amdgcn_mfma_f32_16x16x32_bf16(w1h[0], h1a0, acc1, 0, 0, 0);\
    acc1 = __builtin_amdgcn_mfma_f32_16x16x32_bf16(w1h[1], h1a1, acc1, 0, 0, 0);\
    const unsigned a0 = pk2bf(TANH(acc2[0]), TANH(acc2[1]));                    \
    const unsigned a1 = pk2bf(TANH(acc2[2]), TANH(acc2[3]));                    \
    *(int2*)(&H2s[CUR][li][ubase]) = make_int2((int)a0, (int)a1);               \
    const unsigned c0 = pk2bf(TANH(acc1[0]), TANH(acc1[1]));                    \
    const unsigned c1 = pk2bf(TANH(acc1[2]), TANH(acc1[3]));                    \
    *(int2*)(&H1s[NXT][li][ubase]) = make_int2((int)c0, (int)c1);               \
    if (PF) xw_cur = xwn;                                                       \
    asm volatile("s_waitcnt lgkmcnt(0)\n\ts_barrier" ::: "memory");             \
  }

  // t = 0..77 in pairs (PF always valid: t+2 <= 79), then t = 78 (no PF)
  for (int t = 0; t < SEQ - 2; t += 2) {
    STEP(t, 0, 1, 1)
    STEP(t + 1, 1, 0, 1)
  }
  STEP(SEQ - 2, 0, 1, 0)   // computes h2_78 and h1_79

  // ---- epilogue: h2_79 (cur=1, reads h1_79 from H1s[1], h2_78 from H2s[0]) ----
  {
    const short8 h1a0 = *(const short8*)(&H1s[1][li][quad * 8]);
    const short8 h1a1 = *(const short8*)(&H1s[1][li][32 + quad * 8]);
    const short8 h2a0 = *(const short8*)(&H2s[0][li][quad * 8]);
    const short8 h2a1 = *(const short8*)(&H2s[0][li][32 + quad * 8]);
    floatx4 acc2 = {b2f.x, b2f.y, b2f.z, b2f.w};
    acc2 = __builtin_amdgcn_mfma_f32_16x16x32_bf16(w2x[0], h1a0, acc2, 0, 0, 0);
    acc2 = __builtin_amdgcn_mfma_f32_16x16x32_bf16(w2x[1], h1a1, acc2, 0, 0, 0);
    acc2 = __builtin_amdgcn_mfma_f32_16x16x32_bf16(w2h[0], h2a0, acc2, 0, 0, 0);
    acc2 = __builtin_amdgcn_mfma_f32_16x16x32_bf16(w2h[1], h2a1, acc2, 0, 0, 0);
    const unsigned a0 = pk2bf(TANH(acc2[0]), TANH(acc2[1]));
    const unsigned a1 = pk2bf(TANH(acc2[2]), TANH(acc2[3]));
    *(int2*)(&H2s[1][li][ubase]) = make_int2((int)a0, (int)a1);
  }
  __syncthreads();

  // ---- head: sigmoid(h2_79 @ Wd + bd) ----
  if (tid < MB) {
    const short* hrow = &H2s[1][tid][0];
    float acc = bd[0];
    #pragma unroll
    for (int uu = 0; uu < UNITS; ++uu)
      acc += bf2f(hrow[uu]) * Wd[uu];
    out[rowBase + tid] = 1.0f / (1.0f + __expf(-acc));
  }
#undef STEP
}

extern "C" void kernel_launch(void* const* d_in, const int* in_sizes, int n_in,
                              void* d_out, int out_size, void* d_ws, size_t ws_size,
                              hipStream_t stream) {
  const int*   tokens = (const int*)d_in[0];
  const float* emb    = (const float*)d_in[1];
  const float* W1x    = (const float*)d_in[2];
  const float* W1h    = (const float*)d_in[3];
  const float* b1     = (const float*)d_in[4];
  const float* W2x    = (const float*)d_in[5];
  const float* W2h    = (const float*)d_in[6];
  const float* b2     = (const float*)d_in[7];
  const float* Wd     = (const float*)d_in[8];
  const float* bd     = (const float*)d_in[9];
  float* out = (float*)d_out;
  float* xw  = (float*)d_ws;   // 10000*64*4 = 2.56 MB

  emb_proj_mfma<<<TOTALW / 16, 256, 0, stream>>>(emb, W1x, b1, xw);

  rnn2_kernel<<<BATCH / MB, NTHREADS, 0, stream>>>(tokens, xw, W1h, W2x, W2h,
                                                   b2, Wd, bd, out);
}